// Round 16
// baseline (280.364 us; speedup 1.0000x reference)
//
#include <hip/hip_runtime.h>
#include <hip/hip_bf16.h>

typedef __hip_bfloat16 bf16;
typedef float f32x4 __attribute__((ext_vector_type(4)));
typedef short s16x8 __attribute__((ext_vector_type(8)));

#define B_   16
#define CIN  256
#define CQK  32
#define CV   128
#define VDIM 64
#define TDIM 64
#define P    (VDIM * TDIM)   // 4096

static __device__ __forceinline__ ushort f2bf(float f) {
    bf16 h = __float2bfloat16(f);
    return *(ushort*)&h;
}
static __device__ __forceinline__ float bf2f(ushort u) {
    bf16 h = *(bf16*)&u;
    return __bfloat162float(h);
}

// async 16B-per-lane global -> LDS DMA (LDS dest = wave-uniform base + lane*16)
static __device__ __forceinline__ void gld16(const void* gsrc, void* ldst) {
    __builtin_amdgcn_global_load_lds(
        (const __attribute__((address_space(1))) void*)gsrc,
        (__attribute__((address_space(3))) void*)ldst,
        16, 0, 0);
}

#define MFMA16(A, B, C) __builtin_amdgcn_mfma_f32_16x16x32_bf16((A), (B), (C), 0, 0, 0)

// ---------------------------------------------------------------------------
// repack_all: blocks [0,1024) repack x -> xh/xl; blocks [1024,3904) repack
// weights -> wvT/woT/wqh/wql (+ zero page). One launch (was two).
// ---------------------------------------------------------------------------
__global__ __launch_bounds__(256) void repack_all(
    const float* __restrict__ x,
    const float* __restrict__ wq, const float* __restrict__ wk,
    const float* __restrict__ wv, const float* __restrict__ wo,
    ushort* __restrict__ xhd, ushort* __restrict__ xld,
    ushort* __restrict__ wvT, ushort* __restrict__ woT,
    ushort* __restrict__ wqh, ushort* __restrict__ wql,
    ushort* __restrict__ zp)
{
    if (blockIdx.x >= 1024) {
        if (blockIdx.x == 1024) ((uint*)zp)[threadIdx.x] = 0;   // 1KB zero page
        int i = (blockIdx.x - 1024) * 256 + threadIdx.x;
        const int NQK = 9 * 64 * 256;      // 147456
        const int NV  = 9 * 128 * 256;     // 294912
        if (i < NQK) {
            int tap = i / (64 * 256);
            int r   = i % (64 * 256);
            int oc  = r >> 8;
            int ci  = r & 255;
            const float* src = (oc < 32) ? wq : wk;
            float f = src[(size_t)(oc & 31) * 2304 + ci * 9 + tap];
            ushort h = f2bf(f);
            wqh[i] = h;
            wql[i] = f2bf(f - bf2f(h));
        } else if (i < NQK + NV) {
            i -= NQK;
            int tap = i / (128 * 256);
            int r   = i % (128 * 256);
            int oc  = r >> 8;
            int ci  = r & 255;
            wvT[i] = f2bf(wv[(size_t)oc * 2304 + ci * 9 + tap]);
        } else {
            i -= NQK + NV;
            int tap = i / (256 * 128);
            int r   = i % (256 * 128);
            int oc  = r >> 7;
            int ci  = r & 127;
            woT[i] = f2bf(wo[(size_t)oc * 1152 + ci * 9 + tap]);
        }
        return;
    }
    // x repack: block = (b,y)
    const int b = blockIdx.x >> 6;
    const int y = blockIdx.x & 63;
    __shared__ ushort th[64][257];
    __shared__ ushort tl_[64][257];
    const int t  = threadIdx.x & 63;
    const int cq = threadIdx.x >> 6;
    const float* xb = x + (((size_t)b * CIN) * VDIM + y) * TDIM;
    for (int ci = cq; ci < 256; ci += 4) {
        float f = xb[(size_t)ci * P + t];
        ushort h = f2bf(f);
        th[t][ci]  = h;
        tl_[t][ci] = f2bf(f - bf2f(h));
    }
    __syncthreads();
    const int ci4 = (threadIdx.x & 63) * 4;
    const int tr0 = threadIdx.x >> 6;
    for (int tr = tr0; tr < 64; tr += 4) {
        ushort4 uh, ul;
        uh.x = th[tr][ci4];     uh.y = th[tr][ci4 + 1];
        uh.z = th[tr][ci4 + 2]; uh.w = th[tr][ci4 + 3];
        ul.x = tl_[tr][ci4];     ul.y = tl_[tr][ci4 + 1];
        ul.z = tl_[tr][ci4 + 2]; ul.w = tl_[tr][ci4 + 3];
        const size_t o = ((((size_t)b * 64 + tr) * 64 + y) * 256 + ci4);
        *(ushort4*)(xhd + o) = uh;
        *(ushort4*)(xld + o) = ul;
    }
}

// ---------------------------------------------------------------------------
// Stage one [4 dx][66 yl][128 ci] tile (264 rows x 256B = 67.6KB) via gload_lds.
// 8-wave split: 9/9/8/8/8/8/8/8 of the 66 1KB-DMA rows. Swizzle in source.
// ---------------------------------------------------------------------------
#define STAGE8(SRC, CI0)                                                          \
    {                                                                             \
        const int i0 = (w < 2) ? w * 9 : 18 + (w - 2) * 8;                        \
        const int nr = (w < 2) ? 9 : 8;                                           \
        for (int j = 0; j < nr; ++j) {                                            \
            const int ii  = i0 + j;                                               \
            const int row = ii * 4 + (lane >> 4);                                 \
            const int dxs = (row * 993) >> 16;                                    \
            const int yl  = row - dxs * 66;                                       \
            const int tp  = t0 + dxs - 1;                                         \
            const int yp  = yl - 1;                                               \
            const int chg = (lane & 15) ^ (row & 7);                              \
            const bool ok = ((unsigned)tp < 64u) && ((unsigned)yp < 64u);         \
            const ushort* sp = ok                                                 \
                ? (SRC) + ((((size_t)b * 64 + tp) * 64 + yp) * 256 + (CI0) + chg * 8) \
                : zp + (size_t)lane * 8;                                          \
            gld16(sp, btile + ii * 1024);                                         \
        }                                                                         \
    }

// Read the 4 B-fragments for dx-slice DXS (0..3) at k-step kk (swizzled read).
#define READ_BFR(BFR, DY, DXS, KK)                                                \
    {                                                                             \
        _Pragma("unroll")                                                         \
        for (int nf = 0; nf < 4; ++nf) {                                          \
            const int ylr = nf * 16 + (lane & 15) + (DY);                         \
            const int row = (DXS) * 66 + ylr;                                     \
            BFR[nf] = *(const s16x8*)(btile + row * 256 +                         \
                       ((((KK) * 64 + (lane >> 4) * 16)) ^ ((row & 7) << 4)));    \
        }                                                                         \
    }

// ---------------------------------------------------------------------------
// qkvattn4: 512-thread block = (b, t-pair); waves 0-3 own column t0, waves
// 4-7 own column t0+1 (homogeneous roles: every wave = R11's per-wave conv,
// 48 acc VGPR -> liveness stays low -> 16 waves/CU, 4/SIMD: 2x R15 TLP).
// Shared halo tile staged once (R14 gain kept). Tails run in PARALLEL in
// disjoint 33KB overlays (smem + col*33792, R12 compressed layout).
// Per-accumulator MFMA order identical to R11/R14 -> same numerics.
// ---------------------------------------------------------------------------
__global__ __launch_bounds__(512) void qkvattn4(
    const ushort* __restrict__ xh, const ushort* __restrict__ xl,
    const ushort* __restrict__ wvT,
    const ushort* __restrict__ wqh, const ushort* __restrict__ wql,
    const ushort* __restrict__ zp,
    float* __restrict__ attn_out, ushort* __restrict__ av)
{
    // XCD-bijective swizzle (512 blocks, 8 XCDs, 64/XCD)
    const int bid  = ((blockIdx.x & 7) << 6) | (blockIdx.x >> 3);
    const int b    = bid >> 5;
    const int t0   = (bid & 31) * 2;
    const int tid  = threadIdx.x;
    const int lane = tid & 63;
    const int w    = tid >> 6;       // 0..7
    const int col  = w >> 2;         // 0 or 1: which t-column this wave owns
    const int w4   = w & 3;          // wave index within the column group

    __shared__ __align__(16) char smem[67584];
    char* btile = smem;

    f32x4 accv[2][4];
    f32x4 accq[4];
#pragma unroll
    for (int m = 0; m < 2; ++m)
#pragma unroll
        for (int nf = 0; nf < 4; ++nf) accv[m][nf] = (f32x4){0.f, 0.f, 0.f, 0.f};
#pragma unroll
    for (int nf = 0; nf < 4; ++nf) accq[nf] = (f32x4){0.f, 0.f, 0.f, 0.f};

    const int ocv  = w4 * 32 + (lane & 15);       // v channel base (m adds 16)
    const int ocqk = w4 * 16 + (lane & 15);       // combined q|k channel
    const int ko8  = (lane >> 4) * 8;

#define WVO(TAP, M, KK) (const s16x8*)(wvT + (size_t)((TAP) * 128 + ocv + (M) * 16) * 256 + ci0 + (KK) * 32 + ko8)
#define WQO(ARR, TAP, KK) (const s16x8*)((ARR) + (size_t)((TAP) * 64 + ocqk) * 256 + ci0 + (KK) * 32 + ko8)

    for (int chunk = 0; chunk < 2; ++chunk) {
        const int ci0 = chunk * 128;

        __syncthreads();              // protect btile from prior readers
        STAGE8(xh, ci0)
        __syncthreads();              // drains vmcnt -> DMAs complete

        // ---- merged v + qk-hi pass over x_hi (own column only) ----
#pragma unroll 1
        for (int tap = 0; tap < 9; ++tap) {
            const int dy = tap / 3, dxp = tap % 3;
            s16x8 va[4], vb[4], ha[4], la[4];
#pragma unroll
            for (int kk = 0; kk < 4; ++kk) {
                va[kk] = *WVO(tap, 0, kk);
                vb[kk] = *WVO(tap, 1, kk);
                ha[kk] = *WQO(wqh, tap, kk);
                la[kk] = *WQO(wql, tap, kk);
            }
#pragma unroll
            for (int kk = 0; kk < 4; ++kk) {
                s16x8 bfr[4];
                READ_BFR(bfr, dy, dxp + col, kk)
#pragma unroll
                for (int nf = 0; nf < 4; ++nf)
                    accv[0][nf] = MFMA16(va[kk], bfr[nf], accv[0][nf]);
#pragma unroll
                for (int nf = 0; nf < 4; ++nf)
                    accv[1][nf] = MFMA16(vb[kk], bfr[nf], accv[1][nf]);
#pragma unroll
                for (int nf = 0; nf < 4; ++nf)
                    accq[nf] = MFMA16(ha[kk], bfr[nf], accq[nf]);
#pragma unroll
                for (int nf = 0; nf < 4; ++nf)
                    accq[nf] = MFMA16(la[kk], bfr[nf], accq[nf]);
            }
        }

        __syncthreads();              // all reads of x_hi tile done
        STAGE8(xl, ci0)
        __syncthreads();

        // ---- qk lo pass (w_hi . x_lo), own column ----
#pragma unroll 1
        for (int tap = 0; tap < 9; ++tap) {
            const int dy = tap / 3, dxp = tap % 3;
            s16x8 ha[4];
#pragma unroll
            for (int kk = 0; kk < 4; ++kk) ha[kk] = *WQO(wqh, tap, kk);
#pragma unroll
            for (int kk = 0; kk < 4; ++kk) {
                s16x8 bfr[4];
                READ_BFR(bfr, dy, dxp + col, kk)
#pragma unroll
                for (int nf = 0; nf < 4; ++nf)
                    accq[nf] = MFMA16(ha[kk], bfr[nf], accq[nf]);
            }
        }
    }
#undef WVO
#undef WQO
    __syncthreads();   // btile dead; repurpose LDS for the two parallel tails

    const int l15 = lane & 15, lg = lane >> 4;
    char* ovl = smem + col * 33792;   // per-column 33KB tail overlay

    // ---- phase A: conv accumulators -> overlay (q@0/k@8192 hi|lo, vsT@16384) ----
    {
        char* qkb = ovl + ((w4 < 2) ? 0 : 8192);
        const int c0 = (w4 & 1) * 16 + lg * 4;
#pragma unroll
        for (int nf = 0; nf < 4; ++nf) {
            const int y = nf * 16 + l15;
            ushort4 h4, l4;
#pragma unroll
            for (int r = 0; r < 4; ++r) {
                ushort h = f2bf(accq[nf][r]);
                ((ushort*)&h4)[r] = h;
                ((ushort*)&l4)[r] = f2bf(accq[nf][r] - bf2f(h));
            }
            const int swz = (y & 7) << 4;
            *(ushort4*)(qkb + y * 128 + ((2 * c0) ^ swz))      = h4;
            *(ushort4*)(qkb + y * 128 + ((64 + 2 * c0) ^ swz)) = l4;
        }
        // vsT[c][j] = v[j][c] (bf16), swizzled rows
#pragma unroll
        for (int m = 0; m < 2; ++m)
#pragma unroll
            for (int nf = 0; nf < 4; ++nf) {
                const int y = nf * 16 + l15;
#pragma unroll
                for (int r = 0; r < 4; ++r) {
                    const int oc = w4 * 32 + m * 16 + lg * 4 + r;
                    *(ushort*)(ovl + 16384 + oc * 128 + ((2 * y) ^ ((oc & 7) << 4)))
                        = f2bf(accv[m][nf][r]);
                }
            }
    }
    __syncthreads();

    // ---- phase B: S via MFMA (3-pass), softmax in-register; P overlays q/k ----
    f32x4 pv[4];
    {
        const int yq = w4 * 16 + l15;
        const int sq = (yq & 7) << 4;
        s16x8 qh = *(const s16x8*)(ovl + yq * 128 + ((lg * 16) ^ sq));
        s16x8 ql = *(const s16x8*)(ovl + yq * 128 + ((64 + lg * 16) ^ sq));
        s16x8 kh[4], kl[4];
#pragma unroll
        for (int jt = 0; jt < 4; ++jt) {
            const int jr = jt * 16 + l15;
            const int sk = (jr & 7) << 4;
            kh[jt] = *(const s16x8*)(ovl + 8192 + jr * 128 + ((lg * 16) ^ sk));
            kl[jt] = *(const s16x8*)(ovl + 8192 + jr * 128 + ((64 + lg * 16) ^ sk));
        }
        __syncthreads();   // ALL q/k reads complete -> safe to overlay P

        f32x4 sAcc[4];
#pragma unroll
        for (int jt = 0; jt < 4; ++jt) {
            f32x4 a = (f32x4){0.f, 0.f, 0.f, 0.f};
            a = MFMA16(qh, kh[jt], a);
            a = MFMA16(qh, kl[jt], a);
            a = MFMA16(ql, kh[jt], a);
            sAcc[jt] = a;   // S[w4*16 + lg*4 + r][jt*16 + l15]
        }
        float mx[4], sum[4];
#pragma unroll
        for (int r = 0; r < 4; ++r)
            mx[r] = fmaxf(fmaxf(sAcc[0][r], sAcc[1][r]), fmaxf(sAcc[2][r], sAcc[3][r]));
#pragma unroll
        for (int d = 1; d < 16; d <<= 1)
#pragma unroll
            for (int r = 0; r < 4; ++r) mx[r] = fmaxf(mx[r], __shfl_xor(mx[r], d));
#pragma unroll
        for (int r = 0; r < 4; ++r) sum[r] = 0.f;
#pragma unroll
        for (int jt = 0; jt < 4; ++jt)
#pragma unroll
            for (int r = 0; r < 4; ++r) {
                pv[jt][r] = expf(sAcc[jt][r] - mx[r]);
                sum[r] += pv[jt][r];
            }
#pragma unroll
        for (int d = 1; d < 16; d <<= 1)
#pragma unroll
            for (int r = 0; r < 4; ++r) sum[r] += __shfl_xor(sum[r], d);
#pragma unroll
        for (int r = 0; r < 4; ++r) sum[r] = 1.f / sum[r];
#pragma unroll
        for (int jt = 0; jt < 4; ++jt)
#pragma unroll
            for (int r = 0; r < 4; ++r) pv[jt][r] *= sum[r];

        // attn write (fp32)
        float* ao = attn_out + (size_t)(b * 64 + t0 + col) * 4096;
#pragma unroll
        for (int jt = 0; jt < 4; ++jt)
#pragma unroll
            for (int r = 0; r < 4; ++r)
                ao[(w4 * 16 + lg * 4 + r) * 64 + jt * 16 + l15] = pv[jt][r];

        // P -> bf16 hi@0 / lo@8192 (over dead q/k), swizzled rows
#pragma unroll
        for (int jt = 0; jt < 4; ++jt)
#pragma unroll
            for (int r = 0; r < 4; ++r) {
                const int i = w4 * 16 + lg * 4 + r;
                const int j = jt * 16 + l15;
                const int off = i * 128 + ((2 * j) ^ ((i & 7) << 4));
                ushort h = f2bf(pv[jt][r]);
                *(ushort*)(ovl + off)        = h;
                *(ushort*)(ovl + 8192 + off) = f2bf(pv[jt][r] - bf2f(h));
            }
    }
    __syncthreads();

    // ---- phase C: AV^T = V^T (Phi + Plo) via MFMA; avL overlays vsT ----
    {
        s16x8 vt[2][2];
#pragma unroll
        for (int c2 = 0; c2 < 2; ++c2)
#pragma unroll
            for (int ks = 0; ks < 2; ++ks) {
                const int c = (w4 * 2 + c2) * 16 + l15;
                vt[c2][ks] = *(const s16x8*)(ovl + 16384 + c * 128 +
                                             ((ks * 64 + lg * 16) ^ ((c & 7) << 4)));
            }
        __syncthreads();   // ALL vsT reads complete -> safe to overlay avL

        f32x4 acc2[2][4];
#pragma unroll
        for (int c2 = 0; c2 < 2; ++c2)
#pragma unroll
            for (int it = 0; it < 4; ++it) acc2[c2][it] = (f32x4){0.f, 0.f, 0.f, 0.f};

#pragma unroll
        for (int it = 0; it < 4; ++it) {
            const int i = it * 16 + l15;
            const int si = (i & 7) << 4;
            s16x8 ph[2], pl[2];
#pragma unroll
            for (int ks = 0; ks < 2; ++ks) {
                ph[ks] = *(const s16x8*)(ovl + i * 128 + ((ks * 64 + lg * 16) ^ si));
                pl[ks] = *(const s16x8*)(ovl + 8192 + i * 128 + ((ks * 64 + lg * 16) ^ si));
            }
#pragma unroll
            for (int c2 = 0; c2 < 2; ++c2)
#pragma unroll
                for (int ks = 0; ks < 2; ++ks) {
                    acc2[c2][it] = MFMA16(vt[c2][ks], ph[ks], acc2[c2][it]);
                    acc2[c2][it] = MFMA16(vt[c2][ks], pl[ks], acc2[c2][it]);
                }
        }
        // avL[i][c] (bf16) swizzled [64][256B] rows at ovl+16384
#pragma unroll
        for (int c2 = 0; c2 < 2; ++c2)
#pragma unroll
            for (int it = 0; it < 4; ++it)
#pragma unroll
                for (int r = 0; r < 4; ++r) {
                    const int c = (w4 * 2 + c2) * 16 + lg * 4 + r;
                    const int i = it * 16 + l15;
                    *(ushort*)(ovl + 16384 + i * 256 + ((2 * c) ^ ((i & 7) << 4)))
                        = f2bf(acc2[c2][it][r]);
                }
    }
    __syncthreads();

    // ---- phase D: avL -> global, coalesced; 256 threads per column ----
    {
        const int tc = tid & 255;
        uint* avg = (uint*)(av + (size_t)(b * 64 + t0 + col) * 8192);
#pragma unroll
        for (int t = 0; t < 16; ++t) {
            const int idx = t * 256 + tc;
            const int i  = idx >> 6;
            const int cc = idx & 63;
            avg[idx] = *(const uint*)(ovl + 16384 + i * 256 + ((4 * cc) ^ ((i & 7) << 4)));
        }
    }
}

// ---------------------------------------------------------------------------
// out_conv_mfma2: 512-thread / 8-wave block = (b, y-pair). (R15, unchanged)
// ---------------------------------------------------------------------------
__global__ __launch_bounds__(512) void out_conv_mfma2(
    const float* __restrict__ x,
    const ushort* __restrict__ av,
    const ushort* __restrict__ woT,
    const ushort* __restrict__ zp,
    const float* __restrict__ sigma,
    float* __restrict__ out)
{
    // XCD-bijective swizzle (512 blocks, 64/XCD)
    const int bid  = ((blockIdx.x & 7) << 6) | (blockIdx.x >> 3);
    const int y0   = (bid & 31) * 2;
    const int b    = bid >> 5;
    const int tid  = threadIdx.x;
    const int lane = tid & 63;
    const int w    = tid >> 6;           // 0..7

    __shared__ __align__(16) char smem[67584];
    char* btile = smem;

    f32x4 acc[2][2][4];   // [col][m][nf]
#pragma unroll
    for (int c = 0; c < 2; ++c)
#pragma unroll
        for (int m = 0; m < 2; ++m)
#pragma unroll
            for (int nf = 0; nf < 4; ++nf) acc[c][m][nf] = (f32x4){0.f, 0.f, 0.f, 0.f};

    // stage [4 dy][66 tl][128 ci] from av (dy spans y0-1..y0+2); 66 DMA rows
    // split 9/9/8/8/8/8/8/8 across 8 waves. Swizzle folded into source.
    {
        const int i0 = (w < 2) ? w * 9 : 18 + (w - 2) * 8;
        const int ni = (w < 2) ? 9 : 8;
        for (int j = 0; j < ni; ++j) {
            const int ii  = i0 + j;
            const int row = ii * 4 + (lane >> 4);
            const int dys = (row * 993) >> 16;
            const int tl  = row - dys * 66;
            const int yp  = y0 + dys - 1;
            const int tp  = tl - 1;
            const int chg = (lane & 15) ^ (row & 7);
            const bool ok = ((unsigned)yp < 64u) && ((unsigned)tp < 64u);
            const ushort* sp = ok
                ? av + ((((size_t)b * 64 + tp) * 64 + yp) * 128 + chg * 8)
                : zp + (size_t)lane * 8;
            gld16(sp, btile + ii * 1024);
        }
    }
    __syncthreads();

    const int oc  = w * 32 + (lane & 15);
    const int ko8 = (lane >> 4) * 8;
#define WOO(TAP, M, KK) (const s16x8*)(woT + (size_t)((TAP) * 256 + oc + (M) * 16) * 128 + (KK) * 32 + ko8)
#pragma unroll 1
    for (int tap = 0; tap < 9; ++tap) {
        const int dy = tap / 3, dxp = tap % 3;
        s16x8 wa[4], wb[4];
#pragma unroll
        for (int kk = 0; kk < 4; ++kk) {
            wa[kk] = *WOO(tap, 0, kk);
            wb[kk] = *WOO(tap, 1, kk);
        }
#pragma unroll
        for (int kk = 0; kk < 4; ++kk) {
#pragma unroll
            for (int col = 0; col < 2; ++col) {
                s16x8 bfr[4];
#pragma unroll
                for (int nf = 0; nf < 4; ++nf) {
                    const int tl = nf * 16 + (lane & 15) + dxp;
                    const int row = (dy + col) * 66 + tl;
                    const int bir = kk * 64 + (lane >> 4) * 16;
                    bfr[nf] = *(const s16x8*)(btile + row * 256 + (bir ^ ((row & 7) << 4)));
                }
#pragma unroll
                for (int nf = 0; nf < 4; ++nf)
                    acc[col][0][nf] = MFMA16(wa[kk], bfr[nf], acc[col][0][nf]);
#pragma unroll
                for (int nf = 0; nf < 4; ++nf)
                    acc[col][1][nf] = MFMA16(wb[kk], bfr[nf], acc[col][1][nf]);
            }
        }
    }
#undef WOO

    const float s = sigma[0];
#pragma unroll
    for (int col = 0; col < 2; ++col)
#pragma unroll
        for (int m = 0; m < 2; ++m)
#pragma unroll
            for (int nf = 0; nf < 4; ++nf)
#pragma unroll
                for (int r = 0; r < 4; ++r) {
                    const int occ = w * 32 + m * 16 + (lane >> 4) * 4 + r;
                    const int t   = nf * 16 + (lane & 15);
                    const size_t a = (((size_t)b * 256 + occ) * 64 + (y0 + col)) * 64 + t;
                    out[a] = x[a] + s * acc[col][m][nf][r];
                }
}

// ---------------------------------------------------------------------------
extern "C" void kernel_launch(void* const* d_in, const int* in_sizes, int n_in,
                              void* d_out, int out_size, void* d_ws, size_t ws_size,
                              hipStream_t stream)
{
    const float* x     = (const float*)d_in[0];
    const float* wq    = (const float*)d_in[1];
    const float* wk    = (const float*)d_in[2];
    const float* wv    = (const float*)d_in[3];
    const float* wo    = (const float*)d_in[4];
    const float* sigma = (const float*)d_in[5];

    float* out      = (float*)d_out;                 // [16,256,64,64]
    float* attn_out = out + (size_t)16777216;        // [1024,64,64]

    // x hi/lo bf16 alias the out-image region (dead until out_conv_mfma2):
    ushort* xh = (ushort*)d_out;                     // 16,777,216 bf16 = 32 MiB
    ushort* xl = xh + (size_t)16777216;              // 32 MiB (ends at attn_out)

    // d_ws: av | weights | zero page (~17.7 MiB)
    ushort* av  = (ushort*)d_ws;                     // 8,388,608 bf16
    ushort* wvT = av + 8388608;                      // 294,912
    ushort* woT = wvT + 294912;                      // 294,912
    ushort* wqh = woT + 294912;                      // 147,456
    ushort* wql = wqh + 147456;                      // 147,456
    ushort* zp  = wql + 147456;                      // 512 (1 KB zero page)

    repack_all<<<1024 + 2880, 256, 0, stream>>>(x, wq, wk, wv, wo,
                                                xh, xl, wvT, woT, wqh, wql, zp);
    qkvattn4<<<B_ * 32, 512, 0, stream>>>(xh, xl, wvT, wqh, wql, zp, attn_out, av);
    out_conv_mfma2<<<B_ * 32, 512, 0, stream>>>(x, av, woT, zp, sigma, out);
}

// Round 17
// 150.927 us; speedup vs baseline: 1.8576x; 1.8576x over previous
//
#include <hip/hip_runtime.h>
#include <hip/hip_bf16.h>

typedef __hip_bfloat16 bf16;
typedef float f32x4 __attribute__((ext_vector_type(4)));
typedef short s16x8 __attribute__((ext_vector_type(8)));

#define B_   16
#define CIN  256
#define CQK  32
#define CV   128
#define VDIM 64
#define TDIM 64
#define P    (VDIM * TDIM)   // 4096

static __device__ __forceinline__ ushort f2bf(float f) {
    bf16 h = __float2bfloat16(f);
    return *(ushort*)&h;
}
static __device__ __forceinline__ float bf2f(ushort u) {
    bf16 h = *(bf16*)&u;
    return __bfloat162float(h);
}

// async 16B-per-lane global -> LDS DMA (LDS dest = wave-uniform base + lane*16)
static __device__ __forceinline__ void gld16(const void* gsrc, void* ldst) {
    __builtin_amdgcn_global_load_lds(
        (const __attribute__((address_space(1))) void*)gsrc,
        (__attribute__((address_space(3))) void*)ldst,
        16, 0, 0);
}

#define MFMA16(A, B, C) __builtin_amdgcn_mfma_f32_16x16x32_bf16((A), (B), (C), 0, 0, 0)

// ---------------------------------------------------------------------------
// repack_all: blocks [0,1024) repack x -> xh (bf16); blocks [1024,3904)
// repack weights -> wvT/woT/wqh (+ zero page). Split-bf16 conv removed (R17):
// no xl, no wql — 1-pass bf16 q/k conv; fp32 S-split happens in the tail.
// ---------------------------------------------------------------------------
__global__ __launch_bounds__(256) void repack_all(
    const float* __restrict__ x,
    const float* __restrict__ wq, const float* __restrict__ wk,
    const float* __restrict__ wv, const float* __restrict__ wo,
    ushort* __restrict__ xhd,
    ushort* __restrict__ wvT, ushort* __restrict__ woT,
    ushort* __restrict__ wqh,
    ushort* __restrict__ zp)
{
    if (blockIdx.x >= 1024) {
        if (blockIdx.x == 1024) ((uint*)zp)[threadIdx.x] = 0;   // 1KB zero page
        int i = (blockIdx.x - 1024) * 256 + threadIdx.x;
        const int NQK = 9 * 64 * 256;      // 147456
        const int NV  = 9 * 128 * 256;     // 294912
        if (i < NQK) {
            int tap = i / (64 * 256);
            int r   = i % (64 * 256);
            int oc  = r >> 8;
            int ci  = r & 255;
            const float* src = (oc < 32) ? wq : wk;
            wqh[i] = f2bf(src[(size_t)(oc & 31) * 2304 + ci * 9 + tap]);
        } else if (i < NQK + NV) {
            i -= NQK;
            int tap = i / (128 * 256);
            int r   = i % (128 * 256);
            int oc  = r >> 8;
            int ci  = r & 255;
            wvT[i] = f2bf(wv[(size_t)oc * 2304 + ci * 9 + tap]);
        } else {
            i -= NQK + NV;
            int tap = i / (256 * 128);
            int r   = i % (256 * 128);
            int oc  = r >> 7;
            int ci  = r & 127;
            woT[i] = f2bf(wo[(size_t)oc * 1152 + ci * 9 + tap]);
        }
        return;
    }
    // x repack: block = (b,y) -> xh [B][64t][64y][256ci] bf16
    const int b = blockIdx.x >> 6;
    const int y = blockIdx.x & 63;
    __shared__ ushort th[64][257];
    const int t  = threadIdx.x & 63;
    const int cq = threadIdx.x >> 6;
    const float* xb = x + (((size_t)b * CIN) * VDIM + y) * TDIM;
    for (int ci = cq; ci < 256; ci += 4)
        th[t][ci] = f2bf(xb[(size_t)ci * P + t]);
    __syncthreads();
    const int ci4 = (threadIdx.x & 63) * 4;
    const int tr0 = threadIdx.x >> 6;
    for (int tr = tr0; tr < 64; tr += 4) {
        ushort4 uh;
        uh.x = th[tr][ci4];     uh.y = th[tr][ci4 + 1];
        uh.z = th[tr][ci4 + 2]; uh.w = th[tr][ci4 + 3];
        *(ushort4*)(xhd + ((((size_t)b * 64 + tr) * 64 + y) * 256 + ci4)) = uh;
    }
}

// ---------------------------------------------------------------------------
// Stage one [4 dx][66 yl][128 ci] tile (264 rows x 256B = 67.6KB) via gload_lds.
// dx spans t0-1 .. t0+2 (shared halo for the 2-column block). 66 DMA instrs
// split 17/17/16/16 across waves. Swizzle folded into source channel.
// ---------------------------------------------------------------------------
#define STAGE2(SRC, CI0)                                                          \
    {                                                                             \
        const int i0 = (w < 2) ? w * 17 : 34 + (w - 2) * 16;                      \
        const int nr = (w < 2) ? 17 : 16;                                         \
        for (int j = 0; j < nr; ++j) {                                            \
            const int ii  = i0 + j;                                               \
            const int row = ii * 4 + (lane >> 4);                                 \
            const int dxs = (row * 993) >> 16;                                    \
            const int yl  = row - dxs * 66;                                       \
            const int tp  = t0 + dxs - 1;                                         \
            const int yp  = yl - 1;                                               \
            const int chg = (lane & 15) ^ (row & 7);                              \
            const bool ok = ((unsigned)tp < 64u) && ((unsigned)yp < 64u);         \
            const ushort* sp = ok                                                 \
                ? (SRC) + ((((size_t)b * 64 + tp) * 64 + yp) * 256 + (CI0) + chg * 8) \
                : zp + (size_t)lane * 8;                                          \
            gld16(sp, btile + ii * 1024);                                         \
        }                                                                         \
    }

// Read the 4 B-fragments for dx-slice DXS (0..3) at k-step kk (swizzled read).
#define READ_BFR(BFR, DY, DXS, KK)                                                \
    {                                                                             \
        _Pragma("unroll")                                                         \
        for (int nf = 0; nf < 4; ++nf) {                                          \
            const int ylr = nf * 16 + (lane & 15) + (DY);                         \
            const int row = (DXS) * 66 + ylr;                                     \
            BFR[nf] = *(const s16x8*)(btile + row * 256 +                         \
                       ((((KK) * 64 + (lane >> 4) * 16)) ^ ((row & 7) << 4)));    \
        }                                                                         \
    }

// ---------------------------------------------------------------------------
// qkvattn2: fused q/k/v conv + MFMA attention, TWO t-columns per block
// (R14/R15 structure). R17 change: q/k conv is 1-pass bf16 (no w_lo/x_lo
// correction passes) — 2 stage phases instead of 4, 12 weight frags/tap,
// accq gets only ha. v path bitwise-identical. The tail still splits the
// fp32 accq hi/lo for the S MFMA (full accumulator precision preserved).
// ---------------------------------------------------------------------------
__global__ __launch_bounds__(256) void qkvattn2(
    const ushort* __restrict__ xh,
    const ushort* __restrict__ wvT,
    const ushort* __restrict__ wqh,
    const ushort* __restrict__ zp,
    float* __restrict__ attn_out, ushort* __restrict__ av)
{
    // XCD-bijective swizzle (512 blocks, 8 XCDs, 64/XCD)
    const int bid  = ((blockIdx.x & 7) << 6) | (blockIdx.x >> 3);
    const int b    = bid >> 5;
    const int t0   = (bid & 31) * 2;
    const int tid  = threadIdx.x;
    const int lane = tid & 63;
    const int w    = tid >> 6;

    __shared__ __align__(16) char smem[67584];
    char* btile = smem;

    f32x4 accv[2][2][4];   // [col][m][nf]
    f32x4 accq[2][4];      // [col][nf]
#pragma unroll
    for (int c = 0; c < 2; ++c) {
#pragma unroll
        for (int m = 0; m < 2; ++m)
#pragma unroll
            for (int nf = 0; nf < 4; ++nf) accv[c][m][nf] = (f32x4){0.f, 0.f, 0.f, 0.f};
#pragma unroll
        for (int nf = 0; nf < 4; ++nf) accq[c][nf] = (f32x4){0.f, 0.f, 0.f, 0.f};
    }

    const int ocv  = w * 32 + (lane & 15);        // v channel base (m adds 16)
    const int ocqk = w * 16 + (lane & 15);        // combined q|k channel
    const int ko8  = (lane >> 4) * 8;

#define WVO(TAP, M, KK) (const s16x8*)(wvT + (size_t)((TAP) * 128 + ocv + (M) * 16) * 256 + ci0 + (KK) * 32 + ko8)
#define WQO(TAP, KK) (const s16x8*)(wqh + (size_t)((TAP) * 64 + ocqk) * 256 + ci0 + (KK) * 32 + ko8)

    for (int chunk = 0; chunk < 2; ++chunk) {
        const int ci0 = chunk * 128;

        __syncthreads();              // protect btile from prior readers
        STAGE2(xh, ci0)
        __syncthreads();              // drains vmcnt -> DMAs complete

        // ---- merged v + qk pass: one weight batch, 2 columns ----
#pragma unroll 1
        for (int tap = 0; tap < 9; ++tap) {
            const int dy = tap / 3, dxp = tap % 3;
            s16x8 va[4], vb[4], ha[4];
#pragma unroll
            for (int kk = 0; kk < 4; ++kk) {
                va[kk] = *WVO(tap, 0, kk);
                vb[kk] = *WVO(tap, 1, kk);
                ha[kk] = *WQO(tap, kk);
            }
#pragma unroll
            for (int kk = 0; kk < 4; ++kk) {
                s16x8 bfr[4];
                READ_BFR(bfr, dy, dxp, kk)          // column 0
#pragma unroll
                for (int nf = 0; nf < 4; ++nf)
                    accv[0][0][nf] = MFMA16(va[kk], bfr[nf], accv[0][0][nf]);
#pragma unroll
                for (int nf = 0; nf < 4; ++nf)
                    accv[0][1][nf] = MFMA16(vb[kk], bfr[nf], accv[0][1][nf]);
#pragma unroll
                for (int nf = 0; nf < 4; ++nf)
                    accq[0][nf] = MFMA16(ha[kk], bfr[nf], accq[0][nf]);

                s16x8 bfr1[4];
                READ_BFR(bfr1, dy, dxp + 1, kk)     // column 1 (same weights)
#pragma unroll
                for (int nf = 0; nf < 4; ++nf)
                    accv[1][0][nf] = MFMA16(va[kk], bfr1[nf], accv[1][0][nf]);
#pragma unroll
                for (int nf = 0; nf < 4; ++nf)
                    accv[1][1][nf] = MFMA16(vb[kk], bfr1[nf], accv[1][1][nf]);
#pragma unroll
                for (int nf = 0; nf < 4; ++nf)
                    accq[1][nf] = MFMA16(ha[kk], bfr1[nf], accq[1][nf]);
            }
        }
    }
#undef WVO
#undef WQO
    __syncthreads();   // btile dead; repurpose LDS for MFMA attention

    const int l15 = lane & 15, lg = lane >> 4;

    // ---- attention tail, per column (R12 compressed 32KB layout) ----
#pragma unroll
    for (int col = 0; col < 2; ++col) {
        // phase A: conv accumulators -> LDS (q@0 / k@8192 hi|lo, vsT@16384)
        {
            char* qkb = smem + ((w < 2) ? 0 : 8192);
            const int c0 = (w & 1) * 16 + lg * 4;
#pragma unroll
            for (int nf = 0; nf < 4; ++nf) {
                const int y = nf * 16 + l15;
                ushort4 h4, l4;
#pragma unroll
                for (int r = 0; r < 4; ++r) {
                    ushort h = f2bf(accq[col][nf][r]);
                    ((ushort*)&h4)[r] = h;
                    ((ushort*)&l4)[r] = f2bf(accq[col][nf][r] - bf2f(h));
                }
                const int swz = (y & 7) << 4;
                *(ushort4*)(qkb + y * 128 + ((2 * c0) ^ swz))      = h4;
                *(ushort4*)(qkb + y * 128 + ((64 + 2 * c0) ^ swz)) = l4;
            }
#pragma unroll
            for (int m = 0; m < 2; ++m)
#pragma unroll
                for (int nf = 0; nf < 4; ++nf) {
                    const int y = nf * 16 + l15;
#pragma unroll
                    for (int r = 0; r < 4; ++r) {
                        const int oc = w * 32 + m * 16 + lg * 4 + r;
                        *(ushort*)(smem + 16384 + oc * 128 + ((2 * y) ^ ((oc & 7) << 4)))
                            = f2bf(accv[col][m][nf][r]);
                    }
                }
        }
        __syncthreads();

        // phase B: S via MFMA (3-pass), softmax in-register; P overlays q/k
        f32x4 pv[4];
        {
            const int yq = w * 16 + l15;
            const int sq = (yq & 7) << 4;
            s16x8 qh = *(const s16x8*)(smem + yq * 128 + ((lg * 16) ^ sq));
            s16x8 ql = *(const s16x8*)(smem + yq * 128 + ((64 + lg * 16) ^ sq));
            s16x8 kh[4], kl[4];
#pragma unroll
            for (int jt = 0; jt < 4; ++jt) {
                const int jr = jt * 16 + l15;
                const int sk = (jr & 7) << 4;
                kh[jt] = *(const s16x8*)(smem + 8192 + jr * 128 + ((lg * 16) ^ sk));
                kl[jt] = *(const s16x8*)(smem + 8192 + jr * 128 + ((64 + lg * 16) ^ sk));
            }
            __syncthreads();   // ALL q/k reads complete -> safe to overlay P

            f32x4 sAcc[4];
#pragma unroll
            for (int jt = 0; jt < 4; ++jt) {
                f32x4 a = (f32x4){0.f, 0.f, 0.f, 0.f};
                a = MFMA16(qh, kh[jt], a);
                a = MFMA16(qh, kl[jt], a);
                a = MFMA16(ql, kh[jt], a);
                sAcc[jt] = a;
            }
            float mx[4], sum[4];
#pragma unroll
            for (int r = 0; r < 4; ++r)
                mx[r] = fmaxf(fmaxf(sAcc[0][r], sAcc[1][r]), fmaxf(sAcc[2][r], sAcc[3][r]));
#pragma unroll
            for (int d = 1; d < 16; d <<= 1)
#pragma unroll
                for (int r = 0; r < 4; ++r) mx[r] = fmaxf(mx[r], __shfl_xor(mx[r], d));
#pragma unroll
            for (int r = 0; r < 4; ++r) sum[r] = 0.f;
#pragma unroll
            for (int jt = 0; jt < 4; ++jt)
#pragma unroll
                for (int r = 0; r < 4; ++r) {
                    pv[jt][r] = expf(sAcc[jt][r] - mx[r]);
                    sum[r] += pv[jt][r];
                }
#pragma unroll
            for (int d = 1; d < 16; d <<= 1)
#pragma unroll
                for (int r = 0; r < 4; ++r) sum[r] += __shfl_xor(sum[r], d);
#pragma unroll
            for (int r = 0; r < 4; ++r) sum[r] = 1.f / sum[r];
#pragma unroll
            for (int jt = 0; jt < 4; ++jt)
#pragma unroll
                for (int r = 0; r < 4; ++r) pv[jt][r] *= sum[r];

            float* ao = attn_out + (size_t)(b * 64 + t0 + col) * 4096;
#pragma unroll
            for (int jt = 0; jt < 4; ++jt)
#pragma unroll
                for (int r = 0; r < 4; ++r)
                    ao[(w * 16 + lg * 4 + r) * 64 + jt * 16 + l15] = pv[jt][r];

#pragma unroll
            for (int jt = 0; jt < 4; ++jt)
#pragma unroll
                for (int r = 0; r < 4; ++r) {
                    const int i = w * 16 + lg * 4 + r;
                    const int j = jt * 16 + l15;
                    const int off = i * 128 + ((2 * j) ^ ((i & 7) << 4));
                    ushort h = f2bf(pv[jt][r]);
                    *(ushort*)(smem + off)        = h;
                    *(ushort*)(smem + 8192 + off) = f2bf(pv[jt][r] - bf2f(h));
                }
        }
        __syncthreads();

        // phase C: AV^T = V^T (Phi + Plo) via MFMA; avL overlays vsT
        {
            s16x8 vt[2][2];
#pragma unroll
            for (int c2 = 0; c2 < 2; ++c2)
#pragma unroll
                for (int ks = 0; ks < 2; ++ks) {
                    const int c = (w * 2 + c2) * 16 + l15;
                    vt[c2][ks] = *(const s16x8*)(smem + 16384 + c * 128 +
                                                 ((ks * 64 + lg * 16) ^ ((c & 7) << 4)));
                }
            __syncthreads();   // ALL vsT reads complete -> safe to overlay avL

            f32x4 acc2[2][4];
#pragma unroll
            for (int c2 = 0; c2 < 2; ++c2)
#pragma unroll
                for (int it = 0; it < 4; ++it) acc2[c2][it] = (f32x4){0.f, 0.f, 0.f, 0.f};

#pragma unroll
            for (int it = 0; it < 4; ++it) {
                const int i = it * 16 + l15;
                const int si = (i & 7) << 4;
                s16x8 ph[2], pl[2];
#pragma unroll
                for (int ks = 0; ks < 2; ++ks) {
                    ph[ks] = *(const s16x8*)(smem + i * 128 + ((ks * 64 + lg * 16) ^ si));
                    pl[ks] = *(const s16x8*)(smem + 8192 + i * 128 + ((ks * 64 + lg * 16) ^ si));
                }
#pragma unroll
                for (int c2 = 0; c2 < 2; ++c2)
#pragma unroll
                    for (int ks = 0; ks < 2; ++ks) {
                        acc2[c2][it] = MFMA16(vt[c2][ks], ph[ks], acc2[c2][it]);
                        acc2[c2][it] = MFMA16(vt[c2][ks], pl[ks], acc2[c2][it]);
                    }
            }
#pragma unroll
            for (int c2 = 0; c2 < 2; ++c2)
#pragma unroll
                for (int it = 0; it < 4; ++it)
#pragma unroll
                    for (int r = 0; r < 4; ++r) {
                        const int c = (w * 2 + c2) * 16 + lg * 4 + r;
                        const int i = it * 16 + l15;
                        *(ushort*)(smem + 16384 + i * 256 + ((2 * c) ^ ((i & 7) << 4)))
                            = f2bf(acc2[c2][it][r]);
                    }
        }
        __syncthreads();

        // phase D: avL -> global, fully coalesced
        {
            uint* avg = (uint*)(av + (size_t)(b * 64 + t0 + col) * 8192);
#pragma unroll
            for (int t = 0; t < 16; ++t) {
                const int idx = t * 256 + tid;
                const int i  = idx >> 6;
                const int cc = idx & 63;
                avg[idx] = *(const uint*)(smem + 16384 + i * 256 + ((4 * cc) ^ ((i & 7) << 4)));
            }
        }
        __syncthreads();   // protects next column's phase A overlay
    }
}

// ---------------------------------------------------------------------------
// out_conv_mfma2: 512-thread / 8-wave block = (b, y-pair). (R15, unchanged)
// ---------------------------------------------------------------------------
__global__ __launch_bounds__(512) void out_conv_mfma2(
    const float* __restrict__ x,
    const ushort* __restrict__ av,
    const ushort* __restrict__ woT,
    const ushort* __restrict__ zp,
    const float* __restrict__ sigma,
    float* __restrict__ out)
{
    // XCD-bijective swizzle (512 blocks, 64/XCD)
    const int bid  = ((blockIdx.x & 7) << 6) | (blockIdx.x >> 3);
    const int y0   = (bid & 31) * 2;
    const int b    = bid >> 5;
    const int tid  = threadIdx.x;
    const int lane = tid & 63;
    const int w    = tid >> 6;           // 0..7

    __shared__ __align__(16) char smem[67584];
    char* btile = smem;

    f32x4 acc[2][2][4];   // [col][m][nf]
#pragma unroll
    for (int c = 0; c < 2; ++c)
#pragma unroll
        for (int m = 0; m < 2; ++m)
#pragma unroll
            for (int nf = 0; nf < 4; ++nf) acc[c][m][nf] = (f32x4){0.f, 0.f, 0.f, 0.f};

    // stage [4 dy][66 tl][128 ci] from av (dy spans y0-1..y0+2); 66 DMA rows
    // split 9/9/8/8/8/8/8/8 across 8 waves. Swizzle folded into source.
    {
        const int i0 = (w < 2) ? w * 9 : 18 + (w - 2) * 8;
        const int ni = (w < 2) ? 9 : 8;
        for (int j = 0; j < ni; ++j) {
            const int ii  = i0 + j;
            const int row = ii * 4 + (lane >> 4);
            const int dys = (row * 993) >> 16;
            const int tl  = row - dys * 66;
            const int yp  = y0 + dys - 1;
            const int tp  = tl - 1;
            const int chg = (lane & 15) ^ (row & 7);
            const bool ok = ((unsigned)yp < 64u) && ((unsigned)tp < 64u);
            const ushort* sp = ok
                ? av + ((((size_t)b * 64 + tp) * 64 + yp) * 128 + chg * 8)
                : zp + (size_t)lane * 8;
            gld16(sp, btile + ii * 1024);
        }
    }
    __syncthreads();

    const int oc  = w * 32 + (lane & 15);
    const int ko8 = (lane >> 4) * 8;
#define WOO(TAP, M, KK) (const s16x8*)(woT + (size_t)((TAP) * 256 + oc + (M) * 16) * 128 + (KK) * 32 + ko8)
#pragma unroll 1
    for (int tap = 0; tap < 9; ++tap) {
        const int dy = tap / 3, dxp = tap % 3;
        s16x8 wa[4], wb[4];
#pragma unroll
        for (int kk = 0; kk < 4; ++kk) {
            wa[kk] = *WOO(tap, 0, kk);
            wb[kk] = *WOO(tap, 1, kk);
        }
#pragma unroll
        for (int kk = 0; kk < 4; ++kk) {
#pragma unroll
            for (int col = 0; col < 2; ++col) {
                s16x8 bfr[4];
#pragma unroll
                for (int nf = 0; nf < 4; ++nf) {
                    const int tl = nf * 16 + (lane & 15) + dxp;
                    const int row = (dy + col) * 66 + tl;
                    const int bir = kk * 64 + (lane >> 4) * 16;
                    bfr[nf] = *(const s16x8*)(btile + row * 256 + (bir ^ ((row & 7) << 4)));
                }
#pragma unroll
                for (int nf = 0; nf < 4; ++nf)
                    acc[col][0][nf] = MFMA16(wa[kk], bfr[nf], acc[col][0][nf]);
#pragma unroll
                for (int nf = 0; nf < 4; ++nf)
                    acc[col][1][nf] = MFMA16(wb[kk], bfr[nf], acc[col][1][nf]);
            }
        }
    }
#undef WOO

    const float s = sigma[0];
#pragma unroll
    for (int col = 0; col < 2; ++col)
#pragma unroll
        for (int m = 0; m < 2; ++m)
#pragma unroll
            for (int nf = 0; nf < 4; ++nf)
#pragma unroll
                for (int r = 0; r < 4; ++r) {
                    const int occ = w * 32 + m * 16 + (lane >> 4) * 4 + r;
                    const int t   = nf * 16 + (lane & 15);
                    const size_t a = (((size_t)b * 256 + occ) * 64 + (y0 + col)) * 64 + t;
                    out[a] = x[a] + s * acc[col][m][nf][r];
                }
}

// ---------------------------------------------------------------------------
extern "C" void kernel_launch(void* const* d_in, const int* in_sizes, int n_in,
                              void* d_out, int out_size, void* d_ws, size_t ws_size,
                              hipStream_t stream)
{
    const float* x     = (const float*)d_in[0];
    const float* wq    = (const float*)d_in[1];
    const float* wk    = (const float*)d_in[2];
    const float* wv    = (const float*)d_in[3];
    const float* wo    = (const float*)d_in[4];
    const float* sigma = (const float*)d_in[5];

    float* out      = (float*)d_out;                 // [16,256,64,64]
    float* attn_out = out + (size_t)16777216;        // [1024,64,64]

    // xh bf16 aliases the out-image region (dead until out_conv_mfma2):
    ushort* xh = (ushort*)d_out;                     // 16,777,216 bf16 = 32 MiB

    // d_ws: av | weights | zero page (~17.5 MiB)
    ushort* av  = (ushort*)d_ws;                     // 8,388,608 bf16
    ushort* wvT = av + 8388608;                      // 294,912
    ushort* woT = wvT + 294912;                      // 294,912
    ushort* wqh = woT + 294912;                      // 147,456
    ushort* zp  = wqh + 147456;                      // 512 (1 KB zero page)

    repack_all<<<1024 + 2880, 256, 0, stream>>>(x, wq, wk, wv, wo,
                                                xh, wvT, woT, wqh, zp);
    qkvattn2<<<B_ * 32, 256, 0, stream>>>(xh, wvT, wqh, zp, attn_out, av);
    out_conv_mfma2<<<B_ * 32, 512, 0, stream>>>(x, av, woT, zp, sigma, out);
}

// Round 18
// 146.860 us; speedup vs baseline: 1.9090x; 1.0277x over previous
//
#include <hip/hip_runtime.h>
#include <hip/hip_bf16.h>

typedef __hip_bfloat16 bf16;
typedef float f32x4 __attribute__((ext_vector_type(4)));
typedef short s16x8 __attribute__((ext_vector_type(8)));

#define B_   16
#define CIN  256
#define CQK  32
#define CV   128
#define VDIM 64
#define TDIM 64
#define P    (VDIM * TDIM)   // 4096

static __device__ __forceinline__ ushort f2bf(float f) {
    bf16 h = __float2bfloat16(f);
    return *(ushort*)&h;
}
static __device__ __forceinline__ float bf2f(ushort u) {
    bf16 h = *(bf16*)&u;
    return __bfloat162float(h);
}

// async 16B-per-lane global -> LDS DMA (LDS dest = wave-uniform base + lane*16)
static __device__ __forceinline__ void gld16(const void* gsrc, void* ldst) {
    __builtin_amdgcn_global_load_lds(
        (const __attribute__((address_space(1))) void*)gsrc,
        (__attribute__((address_space(3))) void*)ldst,
        16, 0, 0);
}

#define MFMA16(A, B, C) __builtin_amdgcn_mfma_f32_16x16x32_bf16((A), (B), (C), 0, 0, 0)

// ---------------------------------------------------------------------------
// repack_all: blocks [0,1024) repack x -> xh (bf16); blocks [1024,3904)
// repack weights -> wvT/woT/wqh (+ zero page).
// ---------------------------------------------------------------------------
__global__ __launch_bounds__(256) void repack_all(
    const float* __restrict__ x,
    const float* __restrict__ wq, const float* __restrict__ wk,
    const float* __restrict__ wv, const float* __restrict__ wo,
    ushort* __restrict__ xhd,
    ushort* __restrict__ wvT, ushort* __restrict__ woT,
    ushort* __restrict__ wqh,
    ushort* __restrict__ zp)
{
    if (blockIdx.x >= 1024) {
        if (blockIdx.x == 1024) ((uint*)zp)[threadIdx.x] = 0;   // 1KB zero page
        int i = (blockIdx.x - 1024) * 256 + threadIdx.x;
        const int NQK = 9 * 64 * 256;      // 147456
        const int NV  = 9 * 128 * 256;     // 294912
        if (i < NQK) {
            int tap = i / (64 * 256);
            int r   = i % (64 * 256);
            int oc  = r >> 8;
            int ci  = r & 255;
            const float* src = (oc < 32) ? wq : wk;
            wqh[i] = f2bf(src[(size_t)(oc & 31) * 2304 + ci * 9 + tap]);
        } else if (i < NQK + NV) {
            i -= NQK;
            int tap = i / (128 * 256);
            int r   = i % (128 * 256);
            int oc  = r >> 8;
            int ci  = r & 255;
            wvT[i] = f2bf(wv[(size_t)oc * 2304 + ci * 9 + tap]);
        } else {
            i -= NQK + NV;
            int tap = i / (256 * 128);
            int r   = i % (256 * 128);
            int oc  = r >> 7;
            int ci  = r & 127;
            woT[i] = f2bf(wo[(size_t)oc * 1152 + ci * 9 + tap]);
        }
        return;
    }
    // x repack: block = (b,y) -> xh [B][64t][64y][256ci] bf16
    const int b = blockIdx.x >> 6;
    const int y = blockIdx.x & 63;
    __shared__ ushort th[64][257];
    const int t  = threadIdx.x & 63;
    const int cq = threadIdx.x >> 6;
    const float* xb = x + (((size_t)b * CIN) * VDIM + y) * TDIM;
    for (int ci = cq; ci < 256; ci += 4)
        th[t][ci] = f2bf(xb[(size_t)ci * P + t]);
    __syncthreads();
    const int ci4 = (threadIdx.x & 63) * 4;
    const int tr0 = threadIdx.x >> 6;
    for (int tr = tr0; tr < 64; tr += 4) {
        ushort4 uh;
        uh.x = th[tr][ci4];     uh.y = th[tr][ci4 + 1];
        uh.z = th[tr][ci4 + 2]; uh.w = th[tr][ci4 + 3];
        *(ushort4*)(xhd + ((((size_t)b * 64 + tr) * 64 + y) * 256 + ci4)) = uh;
    }
}

// ---------------------------------------------------------------------------
// Stage one [4 dx][66 yl][128 ci] tile (264 rows x 256B = 67.6KB) via gload_lds.
// dx spans t0-1 .. t0+2 (shared halo for the 2-column block). 66 DMA instrs
// split 17/17/16/16 across waves. Swizzle folded into source channel.
// ---------------------------------------------------------------------------
#define STAGE2(SRC, CI0)                                                          \
    {                                                                             \
        const int i0 = (w < 2) ? w * 17 : 34 + (w - 2) * 16;                      \
        const int nr = (w < 2) ? 17 : 16;                                         \
        for (int j = 0; j < nr; ++j) {                                            \
            const int ii  = i0 + j;                                               \
            const int row = ii * 4 + (lane >> 4);                                 \
            const int dxs = (row * 993) >> 16;                                    \
            const int yl  = row - dxs * 66;                                       \
            const int tp  = t0 + dxs - 1;                                         \
            const int yp  = yl - 1;                                               \
            const int chg = (lane & 15) ^ (row & 7);                              \
            const bool ok = ((unsigned)tp < 64u) && ((unsigned)yp < 64u);         \
            const ushort* sp = ok                                                 \
                ? (SRC) + ((((size_t)b * 64 + tp) * 64 + yp) * 256 + (CI0) + chg * 8) \
                : zp + (size_t)lane * 8;                                          \
            gld16(sp, btile + ii * 1024);                                         \
        }                                                                         \
    }

// Read the 4 B-fragments for dx-slice DXS (0..3) at k-step kk (swizzled read).
#define READ_BFR(BFR, DY, DXS, KK)                                                \
    {                                                                             \
        _Pragma("unroll")                                                         \
        for (int nf = 0; nf < 4; ++nf) {                                          \
            const int ylr = nf * 16 + (lane & 15) + (DY);                         \
            const int row = (DXS) * 66 + ylr;                                     \
            BFR[nf] = *(const s16x8*)(btile + row * 256 +                         \
                       ((((KK) * 64 + (lane >> 4) * 16)) ^ ((row & 7) << 4)));    \
        }                                                                         \
    }

// ---------------------------------------------------------------------------
// qkvattn2: fused q/k/v conv + MFMA attention, TWO t-columns per block.
// Conv (R17, unchanged): 1-pass bf16, one weight batch feeds both columns.
// Tail (R18): the two columns' tails run IN PARALLEL — phase A writes both
// columns' accumulators to disjoint 33KB overlays; then waves {0,1} run
// col 0's phases B/C/D while waves {2,3} run col 1's (each wave covers 2
// q-row tiles / 4 c-tiles). 4 barrier phases instead of 8. Per-column
// arithmetic and MFMA order identical -> identical outputs.
// ---------------------------------------------------------------------------
__global__ __launch_bounds__(256) void qkvattn2(
    const ushort* __restrict__ xh,
    const ushort* __restrict__ wvT,
    const ushort* __restrict__ wqh,
    const ushort* __restrict__ zp,
    float* __restrict__ attn_out, ushort* __restrict__ av)
{
    // XCD-bijective swizzle (512 blocks, 8 XCDs, 64/XCD)
    const int bid  = ((blockIdx.x & 7) << 6) | (blockIdx.x >> 3);
    const int b    = bid >> 5;
    const int t0   = (bid & 31) * 2;
    const int tid  = threadIdx.x;
    const int lane = tid & 63;
    const int w    = tid >> 6;

    __shared__ __align__(16) char smem[67584];
    char* btile = smem;

    f32x4 accv[2][2][4];   // [col][m][nf]
    f32x4 accq[2][4];      // [col][nf]
#pragma unroll
    for (int c = 0; c < 2; ++c) {
#pragma unroll
        for (int m = 0; m < 2; ++m)
#pragma unroll
            for (int nf = 0; nf < 4; ++nf) accv[c][m][nf] = (f32x4){0.f, 0.f, 0.f, 0.f};
#pragma unroll
        for (int nf = 0; nf < 4; ++nf) accq[c][nf] = (f32x4){0.f, 0.f, 0.f, 0.f};
    }

    const int ocv  = w * 32 + (lane & 15);        // v channel base (m adds 16)
    const int ocqk = w * 16 + (lane & 15);        // combined q|k channel
    const int ko8  = (lane >> 4) * 8;

#define WVO(TAP, M, KK) (const s16x8*)(wvT + (size_t)((TAP) * 128 + ocv + (M) * 16) * 256 + ci0 + (KK) * 32 + ko8)
#define WQO(TAP, KK) (const s16x8*)(wqh + (size_t)((TAP) * 64 + ocqk) * 256 + ci0 + (KK) * 32 + ko8)

    for (int chunk = 0; chunk < 2; ++chunk) {
        const int ci0 = chunk * 128;

        __syncthreads();              // protect btile from prior readers
        STAGE2(xh, ci0)
        __syncthreads();              // drains vmcnt -> DMAs complete

        // ---- merged v + qk pass: one weight batch, 2 columns ----
#pragma unroll 1
        for (int tap = 0; tap < 9; ++tap) {
            const int dy = tap / 3, dxp = tap % 3;
            s16x8 va[4], vb[4], ha[4];
#pragma unroll
            for (int kk = 0; kk < 4; ++kk) {
                va[kk] = *WVO(tap, 0, kk);
                vb[kk] = *WVO(tap, 1, kk);
                ha[kk] = *WQO(tap, kk);
            }
#pragma unroll
            for (int kk = 0; kk < 4; ++kk) {
                s16x8 bfr[4];
                READ_BFR(bfr, dy, dxp, kk)          // column 0
#pragma unroll
                for (int nf = 0; nf < 4; ++nf)
                    accv[0][0][nf] = MFMA16(va[kk], bfr[nf], accv[0][0][nf]);
#pragma unroll
                for (int nf = 0; nf < 4; ++nf)
                    accv[0][1][nf] = MFMA16(vb[kk], bfr[nf], accv[0][1][nf]);
#pragma unroll
                for (int nf = 0; nf < 4; ++nf)
                    accq[0][nf] = MFMA16(ha[kk], bfr[nf], accq[0][nf]);

                s16x8 bfr1[4];
                READ_BFR(bfr1, dy, dxp + 1, kk)     // column 1 (same weights)
#pragma unroll
                for (int nf = 0; nf < 4; ++nf)
                    accv[1][0][nf] = MFMA16(va[kk], bfr1[nf], accv[1][0][nf]);
#pragma unroll
                for (int nf = 0; nf < 4; ++nf)
                    accv[1][1][nf] = MFMA16(vb[kk], bfr1[nf], accv[1][1][nf]);
#pragma unroll
                for (int nf = 0; nf < 4; ++nf)
                    accq[1][nf] = MFMA16(ha[kk], bfr1[nf], accq[1][nf]);
            }
        }
    }
#undef WVO
#undef WQO
    __syncthreads();   // btile dead; repurpose LDS for the two parallel tails

    const int l15 = lane & 15, lg = lane >> 4;
    const int colw = w >> 1;                 // column this wave serves in B/C/D
    const int w2   = w & 1;                  // wave index within column pair
    char* ovl = smem + colw * 33792;         // this wave's tail overlay

    // ---- phase A: BOTH columns' accumulators -> overlays ----
#pragma unroll
    for (int col = 0; col < 2; ++col) {
        char* o   = smem + col * 33792;
        char* qkb = o + ((w < 2) ? 0 : 8192);
        const int c0 = (w & 1) * 16 + lg * 4;
#pragma unroll
        for (int nf = 0; nf < 4; ++nf) {
            const int y = nf * 16 + l15;
            ushort4 h4, l4;
#pragma unroll
            for (int r = 0; r < 4; ++r) {
                ushort h = f2bf(accq[col][nf][r]);
                ((ushort*)&h4)[r] = h;
                ((ushort*)&l4)[r] = f2bf(accq[col][nf][r] - bf2f(h));
            }
            const int swz = (y & 7) << 4;
            *(ushort4*)(qkb + y * 128 + ((2 * c0) ^ swz))      = h4;
            *(ushort4*)(qkb + y * 128 + ((64 + 2 * c0) ^ swz)) = l4;
        }
        // vsT[c][j] = v[j][c] (bf16), swizzled rows
#pragma unroll
        for (int m = 0; m < 2; ++m)
#pragma unroll
            for (int nf = 0; nf < 4; ++nf) {
                const int y = nf * 16 + l15;
#pragma unroll
                for (int r = 0; r < 4; ++r) {
                    const int oc = w * 32 + m * 16 + lg * 4 + r;
                    *(ushort*)(o + 16384 + oc * 128 + ((2 * y) ^ ((oc & 7) << 4)))
                        = f2bf(accv[col][m][nf][r]);
                }
            }
    }
    __syncthreads();

    // ---- phase B: S via MFMA (3-pass), softmax; P overlays q/k (per column) ----
    {
        s16x8 kh[4], kl[4];
#pragma unroll
        for (int jt = 0; jt < 4; ++jt) {
            const int jr = jt * 16 + l15;
            const int sk = (jr & 7) << 4;
            kh[jt] = *(const s16x8*)(ovl + 8192 + jr * 128 + ((lg * 16) ^ sk));
            kl[jt] = *(const s16x8*)(ovl + 8192 + jr * 128 + ((64 + lg * 16) ^ sk));
        }
        s16x8 qh[2], ql[2];
#pragma unroll
        for (int s = 0; s < 2; ++s) {
            const int yq = (w2 * 2 + s) * 16 + l15;
            const int sq = (yq & 7) << 4;
            qh[s] = *(const s16x8*)(ovl + yq * 128 + ((lg * 16) ^ sq));
            ql[s] = *(const s16x8*)(ovl + yq * 128 + ((64 + lg * 16) ^ sq));
        }
        __syncthreads();   // ALL q/k reads complete (both cols) -> overlay P

        float* ao = attn_out + (size_t)(b * 64 + t0 + colw) * 4096;
#pragma unroll
        for (int s = 0; s < 2; ++s) {
            f32x4 sAcc[4];
#pragma unroll
            for (int jt = 0; jt < 4; ++jt) {
                f32x4 a = (f32x4){0.f, 0.f, 0.f, 0.f};
                a = MFMA16(qh[s], kh[jt], a);
                a = MFMA16(qh[s], kl[jt], a);
                a = MFMA16(ql[s], kh[jt], a);
                sAcc[jt] = a;   // S[(w2*2+s)*16 + lg*4 + r][jt*16 + l15]
            }
            float mx[4], sum[4];
#pragma unroll
            for (int r = 0; r < 4; ++r)
                mx[r] = fmaxf(fmaxf(sAcc[0][r], sAcc[1][r]), fmaxf(sAcc[2][r], sAcc[3][r]));
#pragma unroll
            for (int d = 1; d < 16; d <<= 1)
#pragma unroll
                for (int r = 0; r < 4; ++r) mx[r] = fmaxf(mx[r], __shfl_xor(mx[r], d));
#pragma unroll
            for (int r = 0; r < 4; ++r) sum[r] = 0.f;
            f32x4 pv[4];
#pragma unroll
            for (int jt = 0; jt < 4; ++jt)
#pragma unroll
                for (int r = 0; r < 4; ++r) {
                    pv[jt][r] = expf(sAcc[jt][r] - mx[r]);
                    sum[r] += pv[jt][r];
                }
#pragma unroll
            for (int d = 1; d < 16; d <<= 1)
#pragma unroll
                for (int r = 0; r < 4; ++r) sum[r] += __shfl_xor(sum[r], d);
#pragma unroll
            for (int r = 0; r < 4; ++r) sum[r] = 1.f / sum[r];
#pragma unroll
            for (int jt = 0; jt < 4; ++jt)
#pragma unroll
                for (int r = 0; r < 4; ++r) pv[jt][r] *= sum[r];

            // attn write (fp32)
#pragma unroll
            for (int jt = 0; jt < 4; ++jt)
#pragma unroll
                for (int r = 0; r < 4; ++r)
                    ao[((w2 * 2 + s) * 16 + lg * 4 + r) * 64 + jt * 16 + l15] = pv[jt][r];

            // P -> bf16 hi@0 / lo@8192 (over dead q/k), swizzled rows
#pragma unroll
            for (int jt = 0; jt < 4; ++jt)
#pragma unroll
                for (int r = 0; r < 4; ++r) {
                    const int i = (w2 * 2 + s) * 16 + lg * 4 + r;
                    const int j = jt * 16 + l15;
                    const int off = i * 128 + ((2 * j) ^ ((i & 7) << 4));
                    ushort h = f2bf(pv[jt][r]);
                    *(ushort*)(ovl + off)        = h;
                    *(ushort*)(ovl + 8192 + off) = f2bf(pv[jt][r] - bf2f(h));
                }
        }
    }
    __syncthreads();

    // ---- phase C: AV^T = V^T (Phi + Plo) via MFMA; avL overlays vsT ----
    {
        s16x8 vt[4][2];
#pragma unroll
        for (int c2 = 0; c2 < 4; ++c2)
#pragma unroll
            for (int ks = 0; ks < 2; ++ks) {
                const int c = (w2 * 4 + c2) * 16 + l15;
                vt[c2][ks] = *(const s16x8*)(ovl + 16384 + c * 128 +
                                             ((ks * 64 + lg * 16) ^ ((c & 7) << 4)));
            }
        __syncthreads();   // ALL vsT reads complete -> safe to overlay avL

        f32x4 acc2[4][4];
#pragma unroll
        for (int c2 = 0; c2 < 4; ++c2)
#pragma unroll
            for (int it = 0; it < 4; ++it) acc2[c2][it] = (f32x4){0.f, 0.f, 0.f, 0.f};

#pragma unroll
        for (int it = 0; it < 4; ++it) {
            const int i = it * 16 + l15;
            const int si = (i & 7) << 4;
            s16x8 ph[2], pl[2];
#pragma unroll
            for (int ks = 0; ks < 2; ++ks) {
                ph[ks] = *(const s16x8*)(ovl + i * 128 + ((ks * 64 + lg * 16) ^ si));
                pl[ks] = *(const s16x8*)(ovl + 8192 + i * 128 + ((ks * 64 + lg * 16) ^ si));
            }
#pragma unroll
            for (int c2 = 0; c2 < 4; ++c2)
#pragma unroll
                for (int ks = 0; ks < 2; ++ks) {
                    acc2[c2][it] = MFMA16(vt[c2][ks], ph[ks], acc2[c2][it]);
                    acc2[c2][it] = MFMA16(vt[c2][ks], pl[ks], acc2[c2][it]);
                }
        }
        // avL[i][c] (bf16) swizzled [64][256B] rows at ovl+16384 (ushort4 ok:
        // XOR flips bits>=4, 8B blocks preserved; c0 multiple of 4)
#pragma unroll
        for (int c2 = 0; c2 < 4; ++c2)
#pragma unroll
            for (int it = 0; it < 4; ++it) {
                const int c0 = (w2 * 4 + c2) * 16 + lg * 4;
                const int i  = it * 16 + l15;
                ushort4 u4;
#pragma unroll
                for (int r = 0; r < 4; ++r) ((ushort*)&u4)[r] = f2bf(acc2[c2][it][r]);
                *(ushort4*)(ovl + 16384 + i * 256 + ((2 * c0) ^ ((i & 7) << 4))) = u4;
            }
    }
    __syncthreads();

    // ---- phase D: avL -> global, coalesced; 128 threads per column ----
    {
        const int tc = tid & 127;
        uint* avg = (uint*)(av + (size_t)(b * 64 + t0 + colw) * 8192);
#pragma unroll
        for (int t = 0; t < 32; ++t) {
            const int idx = t * 128 + tc;
            const int i  = idx >> 6;
            const int cc = idx & 63;
            avg[idx] = *(const uint*)(ovl + 16384 + i * 256 + ((4 * cc) ^ ((i & 7) << 4)));
        }
    }
}

// ---------------------------------------------------------------------------
// out_conv_mfma2: 512-thread / 8-wave block = (b, y-pair). (R15, unchanged)
// ---------------------------------------------------------------------------
__global__ __launch_bounds__(512) void out_conv_mfma2(
    const float* __restrict__ x,
    const ushort* __restrict__ av,
    const ushort* __restrict__ woT,
    const ushort* __restrict__ zp,
    const float* __restrict__ sigma,
    float* __restrict__ out)
{
    // XCD-bijective swizzle (512 blocks, 64/XCD)
    const int bid  = ((blockIdx.x & 7) << 6) | (blockIdx.x >> 3);
    const int y0   = (bid & 31) * 2;
    const int b    = bid >> 5;
    const int tid  = threadIdx.x;
    const int lane = tid & 63;
    const int w    = tid >> 6;           // 0..7

    __shared__ __align__(16) char smem[67584];
    char* btile = smem;

    f32x4 acc[2][2][4];   // [col][m][nf]
#pragma unroll
    for (int c = 0; c < 2; ++c)
#pragma unroll
        for (int m = 0; m < 2; ++m)
#pragma unroll
            for (int nf = 0; nf < 4; ++nf) acc[c][m][nf] = (f32x4){0.f, 0.f, 0.f, 0.f};

    // stage [4 dy][66 tl][128 ci] from av (dy spans y0-1..y0+2); 66 DMA rows
    // split 9/9/8/8/8/8/8/8 across 8 waves. Swizzle folded into source.
    {
        const int i0 = (w < 2) ? w * 9 : 18 + (w - 2) * 8;
        const int ni = (w < 2) ? 9 : 8;
        for (int j = 0; j < ni; ++j) {
            const int ii  = i0 + j;
            const int row = ii * 4 + (lane >> 4);
            const int dys = (row * 993) >> 16;
            const int tl  = row - dys * 66;
            const int yp  = y0 + dys - 1;
            const int tp  = tl - 1;
            const int chg = (lane & 15) ^ (row & 7);
            const bool ok = ((unsigned)yp < 64u) && ((unsigned)tp < 64u);
            const ushort* sp = ok
                ? av + ((((size_t)b * 64 + tp) * 64 + yp) * 128 + chg * 8)
                : zp + (size_t)lane * 8;
            gld16(sp, btile + ii * 1024);
        }
    }
    __syncthreads();

    const int oc  = w * 32 + (lane & 15);
    const int ko8 = (lane >> 4) * 8;
#define WOO(TAP, M, KK) (const s16x8*)(woT + (size_t)((TAP) * 256 + oc + (M) * 16) * 128 + (KK) * 32 + ko8)
#pragma unroll 1
    for (int tap = 0; tap < 9; ++tap) {
        const int dy = tap / 3, dxp = tap % 3;
        s16x8 wa[4], wb[4];
#pragma unroll
        for (int kk = 0; kk < 4; ++kk) {
            wa[kk] = *WOO(tap, 0, kk);
            wb[kk] = *WOO(tap, 1, kk);
        }
#pragma unroll
        for (int kk = 0; kk < 4; ++kk) {
#pragma unroll
            for (int col = 0; col < 2; ++col) {
                s16x8 bfr[4];
#pragma unroll
                for (int nf = 0; nf < 4; ++nf) {
                    const int tl = nf * 16 + (lane & 15) + dxp;
                    const int row = (dy + col) * 66 + tl;
                    const int bir = kk * 64 + (lane >> 4) * 16;
                    bfr[nf] = *(const s16x8*)(btile + row * 256 + (bir ^ ((row & 7) << 4)));
                }
#pragma unroll
                for (int nf = 0; nf < 4; ++nf)
                    acc[col][0][nf] = MFMA16(wa[kk], bfr[nf], acc[col][0][nf]);
#pragma unroll
                for (int nf = 0; nf < 4; ++nf)
                    acc[col][1][nf] = MFMA16(wb[kk], bfr[nf], acc[col][1][nf]);
            }
        }
    }
#undef WOO

    const float s = sigma[0];
#pragma unroll
    for (int col = 0; col < 2; ++col)
#pragma unroll
        for (int m = 0; m < 2; ++m)
#pragma unroll
            for (int nf = 0; nf < 4; ++nf)
#pragma unroll
                for (int r = 0; r < 4; ++r) {
                    const int occ = w * 32 + m * 16 + (lane >> 4) * 4 + r;
                    const int t   = nf * 16 + (lane & 15);
                    const size_t a = (((size_t)b * 256 + occ) * 64 + (y0 + col)) * 64 + t;
                    out[a] = x[a] + s * acc[col][m][nf][r];
                }
}

// ---------------------------------------------------------------------------
extern "C" void kernel_launch(void* const* d_in, const int* in_sizes, int n_in,
                              void* d_out, int out_size, void* d_ws, size_t ws_size,
                              hipStream_t stream)
{
    const float* x     = (const float*)d_in[0];
    const float* wq    = (const float*)d_in[1];
    const float* wk    = (const float*)d_in[2];
    const float* wv    = (const float*)d_in[3];
    const float* wo    = (const float*)d_in[4];
    const float* sigma = (const float*)d_in[5];

    float* out      = (float*)d_out;                 // [16,256,64,64]
    float* attn_out = out + (size_t)16777216;        // [1024,64,64]

    // xh bf16 aliases the out-image region (dead until out_conv_mfma2):
    ushort* xh = (ushort*)d_out;                     // 16,777,216 bf16 = 32 MiB

    // d_ws: av | weights | zero page (~17.5 MiB)
    ushort* av  = (ushort*)d_ws;                     // 8,388,608 bf16
    ushort* wvT = av + 8388608;                      // 294,912
    ushort* woT = wvT + 294912;                      // 294,912
    ushort* wqh = woT + 294912;                      // 147,456
    ushort* zp  = wqh + 147456;                      // 512 (1 KB zero page)

    repack_all<<<1024 + 2880, 256, 0, stream>>>(x, wq, wk, wv, wo,
                                                xh, wvT, woT, wqh, zp);
    qkvattn2<<<B_ * 32, 256, 0, stream>>>(xh, wvT, wqh, zp, attn_out, av);
    out_conv_mfma2<<<B_ * 32, 512, 0, stream>>>(x, av, woT, zp, sigma, out);
}